// Round 1
// 587.131 us; speedup vs baseline: 1.0745x; 1.0745x over previous
//
#include <hip/hip_runtime.h>
#include <stdint.h>

#define N      8192
#define FEAT   512
#define HID    64
#define NH     4
#define C1     256          // NH*HID
#define PCH    80           // accA per-head stride (64 data + Z at col 64; 65..79 unused)
#define TC     320          // NH*PCH
#define NCLS   16
#define C2     32           // accB stride (16 data + Z at col 16)
#define IPB    8            // rows per block in k1
#define LOG2E  1.44269504f

typedef __attribute__((ext_vector_type(8))) short bf16x8;
typedef __attribute__((ext_vector_type(4))) float f32x4;

__device__ __forceinline__ float b2f(uint16_t u){
  uint32_t x = ((uint32_t)u) << 16;
  return __builtin_bit_cast(float, x);
}
__device__ __forceinline__ uint16_t f2b(float f){
  uint32_t x = __builtin_bit_cast(uint32_t, f);
  uint32_t r = (x + 0x7fffu + ((x >> 16) & 1u)) >> 16;
  return (uint16_t)r;
}
__device__ __forceinline__ float lrelu(float v, float a){ return fmaxf(v, a * v); }
__device__ __forceinline__ float fexp2(float x){
#if __has_builtin(__builtin_amdgcn_exp2f)
  return __builtin_amdgcn_exp2f(x);
#else
  return exp2f(x);
#endif
}
__device__ __forceinline__ uint32_t pk_bf16(float lo, float hi){
  uint32_t r;
  asm("v_cvt_pk_bf16_f32 %0, %1, %2" : "=v"(r) : "v"(lo), "v"(hi));
  return r;
}

// ---------------------------------------------------------------- k0: Wh -> WhT[k][cc][f]  (fp32)
__global__ void k0_wht(const float* __restrict__ Wh, float* __restrict__ WhT){
  int idx = blockIdx.x * 256 + threadIdx.x;       // 131072 elems, 512 blocks
  int k = idx >> 15;
  int r = idx & 32767;
  int cc = r >> 9, f = r & 511;
  WhT[idx] = Wh[k * 32768 + f * 64 + cc];
}

// ---------------------------------------------------------------- k1: H = x @ Wh  (+ f1,f2 pre-scaled by log2e)
__global__ __launch_bounds__(256) void k1_h(const float* __restrict__ x,
    const float* __restrict__ WhT, const float* __restrict__ ah,
    uint16_t* __restrict__ H, float* __restrict__ f1, float* __restrict__ f2)
{
  __shared__ float4 xs[IPB][128];
  int t = threadIdx.x;
  int i0 = blockIdx.x * IPB;
  for (int r = t; r < IPB * 128; r += 256){
    int ii = r >> 7, o = r & 127;
    xs[ii][o] = *((const float4*)(x + (size_t)(i0 + ii) * FEAT) + o);
  }
  __syncthreads();
  int k = t >> 6, cc = t & 63;
  const float4* wrow = (const float4*)(WhT + k * 32768 + cc * 512);
  float acc[IPB] = {};
  for (int f4 = 0; f4 < 128; ++f4){
    float4 wv = wrow[f4];
    #pragma unroll
    for (int ii = 0; ii < IPB; ++ii){
      float4 xv = xs[ii][f4];
      acc[ii] += xv.x * wv.x + xv.y * wv.y + xv.z * wv.z + xv.w * wv.w;
    }
  }
  float a1 = ah[k * 128 + cc], a2 = ah[k * 128 + 64 + cc];
  #pragma unroll
  for (int ii = 0; ii < IPB; ++ii){
    int i = i0 + ii;
    H[(size_t)i * C1 + t] = f2b(acc[ii]);
    float c1v = acc[ii] * a1, c2v = acc[ii] * a2;
    #pragma unroll
    for (int off = 32; off; off >>= 1){
      c1v += __shfl_down(c1v, off);
      c2v += __shfl_down(c2v, off);
    }
    if (cc == 0){ f1[k * N + i] = c1v * LOG2E; f2[k * N + i] = c2v * LOG2E; }
  }
}

// ---------------------------------------------------------------- k2a: HT[k][p<64][i] = H[i][k*64+p]   (HT = [4][64][8192])
__global__ void k2a_htT(const uint16_t* __restrict__ H, uint16_t* __restrict__ HT){
  __shared__ uint16_t tile[64][65];
  int bid = blockIdx.x;           // 128 i-tiles x 4 heads
  int k = bid & 3, it = bid >> 2;
  int i0 = it * 64;
  int t = threadIdx.x;
  #pragma unroll
  for (int r = 0; r < 4; ++r){
    int ii = r * 16 + (t >> 4);
    int pp = (t & 15) * 4;
    uint2 v = *(const uint2*)(H + (size_t)(i0 + ii) * C1 + k * 64 + pp);
    const uint16_t* s = (const uint16_t*)&v;
    tile[pp + 0][ii] = s[0]; tile[pp + 1][ii] = s[1];
    tile[pp + 2][ii] = s[2]; tile[pp + 3][ii] = s[3];
  }
  __syncthreads();
  #pragma unroll
  for (int r = 0; r < 4; ++r){
    int pp = r * 16 + (t >> 4);
    int ii = (t & 15) * 4;
    uint2 v;
    uint16_t* s = (uint16_t*)&v;
    s[0] = tile[pp][ii + 0]; s[1] = tile[pp][ii + 1];
    s[2] = tile[pp][ii + 2]; s[3] = tile[pp][ii + 3];
    *(uint2*)(HT + (size_t)k * (64 * N) + (size_t)pp * N + i0 + ii) = v;
  }
}

// ---------------------------------------------------------------- k3: phase-A masked-softmax GEMM (512 thr, reg-Z, prefetch)
#define K3_BODY(JC, CUR, NXT)                                                    \
  {                                                                              \
    __syncthreads();                                                             \
    *(uint4*)&Hl[p0][o40 * 8] = h##CUR##0;                                       \
    *(uint4*)&Hl[p1][o40 * 8] = h##CUR##1;                                       \
    const int gjn = js * 2048 + (((JC) + 1) & 63) * 32;                          \
    h##NXT##0 = *(const uint4*)(src0 + gjn);                                     \
    h##NXT##1 = *(const uint4*)(src1 + gjn);                                     \
    _Pragma("unroll")                                                            \
    for (int r = 0; r < 4; ++r) av##NXT[r] = arow[(size_t)(16 * r) * N + gjn];   \
    _Pragma("unroll")                                                            \
    for (int k = 0; k < 4; ++k) f##NXT[k] = f2[(size_t)k * N + gjn + tj];        \
    _Pragma("unroll")                                                            \
    for (int r = 0; r < 4; ++r){                                                 \
      const int i = half + 16 * r;                                               \
      const int a = av##CUR[r];                                                  \
      float e0, e1, e2, e3;                                                      \
      { float s = f1s[0][i] + f##CUR[0]; e0 = fexp2(fmaxf(s, 0.2f * s)); }       \
      { float s = f1s[1][i] + f##CUR[1]; e1 = fexp2(fmaxf(s, 0.2f * s)); }       \
      { float s = f1s[2][i] + f##CUR[2]; e2 = fexp2(fmaxf(s, 0.2f * s)); }       \
      { float s = f1s[3][i] + f##CUR[3]; e3 = fexp2(fmaxf(s, 0.2f * s)); }       \
      if (a <= 0){ e0 = 0.f; e1 = 0.f; e2 = 0.f; e3 = 0.f; }                     \
      dsum[0][r] += e0; dsum[1][r] += e1;                                        \
      dsum[2][r] += e2; dsum[3][r] += e3;                                        \
      uint32_t pk01 = pk_bf16(e0, e1), pk23 = pk_bf16(e2, e3);                   \
      Pl[0][i][tj] = (uint16_t)pk01; Pl[1][i][tj] = (uint16_t)(pk01 >> 16);      \
      Pl[2][i][tj] = (uint16_t)pk23; Pl[3][i][tj] = (uint16_t)(pk23 >> 16);      \
    }                                                                            \
    __syncthreads();                                                             \
    bf16x8 af0 = *(const bf16x8*)&Pl[head][(ith * 2 + 0) * 16 + m][q * 8];       \
    bf16x8 af1 = *(const bf16x8*)&Pl[head][(ith * 2 + 1) * 16 + m][q * 8];       \
    _Pragma("unroll")                                                            \
    for (int ct = 0; ct < 4; ++ct){                                              \
      bf16x8 bfr = *(const bf16x8*)&Hl[head * 64 + ct * 16 + m][q * 8];          \
      acc[0][ct] = __builtin_amdgcn_mfma_f32_16x16x32_bf16(af0, bfr, acc[0][ct], 0, 0, 0); \
      acc[1][ct] = __builtin_amdgcn_mfma_f32_16x16x32_bf16(af1, bfr, acc[1][ct], 0, 0, 0); \
    }                                                                            \
  }

__global__ __launch_bounds__(512, 4) void k3_attA(const int* __restrict__ adj,
    const uint16_t* __restrict__ HT, const float* __restrict__ f1,
    const float* __restrict__ f2, float* __restrict__ accA)
{
  __shared__ uint16_t Pl[NH][64][40];
  __shared__ uint16_t Hl[256][40];
  __shared__ float f1s[NH][64];

  const int t = threadIdx.x;
  const int ibl = blockIdx.x >> 2;
  const int js = blockIdx.x & 3;
  const int gi0 = ibl * 64;

  if (t < 256){ int k = t >> 6, ii = t & 63; f1s[k][ii] = f1[k * N + gi0 + ii]; }

  const int tj   = t & 31;
  const int half = t >> 5;          // 0..15
  const int lane = t & 63;
  const int w    = t >> 6;          // wave 0..7
  const int head = w >> 1;
  const int ith  = w & 1;
  const int m    = lane & 15;
  const int q    = lane >> 4;

  // staging: 256 rows x 4 uint4 chunks = 1024; 512 threads -> 2 each
  const int p0 = t >> 2, o40 = t & 3;
  const int p1 = p0 + 128;
  const uint16_t* src0 = HT + (size_t)p0 * N + o40 * 8;
  const uint16_t* src1 = HT + (size_t)p1 * N + o40 * 8;

  f32x4 acc[2][4] = {};
  float dsum[NH][4] = {};
  const int* arow = adj + (size_t)(gi0 + half) * N + tj;

  uint4 hA0, hA1, hB0, hB1;
  int avA[4], avB[4];
  float fA[4], fB[4];

  {   // prologue: jc = 0
    const int gj0 = js * 2048;
    hA0 = *(const uint4*)(src0 + gj0);
    hA1 = *(const uint4*)(src1 + gj0);
    #pragma unroll
    for (int r = 0; r < 4; ++r) avA[r] = arow[(size_t)(16 * r) * N + gj0];
    #pragma unroll
    for (int k = 0; k < 4; ++k) fA[k] = f2[(size_t)k * N + gj0 + tj];
  }

  for (int jc = 0; jc < 64; jc += 2){
    K3_BODY(jc,     A, B)
    K3_BODY(jc + 1, B, A)
  }

  #pragma unroll
  for (int itl = 0; itl < 2; ++itl)
    #pragma unroll
    for (int ct = 0; ct < 4; ++ct)
      #pragma unroll
      for (int reg = 0; reg < 4; ++reg){
        int gi = gi0 + (ith * 2 + itl) * 16 + q * 4 + reg;
        accA[((size_t)js * N + gi) * TC + head * PCH + ct * 16 + m] = acc[itl][ct][reg];
      }
  #pragma unroll
  for (int k = 0; k < 4; ++k)
    #pragma unroll
    for (int r = 0; r < 4; ++r){
      float v = dsum[k][r];
      v += __shfl_xor(v, 16);
      v += __shfl_xor(v, 8);
      v += __shfl_xor(v, 4);
      v += __shfl_xor(v, 2);
      v += __shfl_xor(v, 1);
      if (tj == 0)
        accA[((size_t)js * N + gi0 + half + 16 * r) * TC + k * PCH + 64] = v;
    }
}

// ---------------------------------------------------------------- k4: reduce partials -> xcat (lrelu 0.01)
__global__ void k4_redA(const float* __restrict__ accA, uint16_t* __restrict__ xcat){
  int i = blockIdx.x;
  int t = threadIdx.x;
  int k = t >> 6, cc = t & 63;
  size_t base = (size_t)i * TC + k * PCH;
  float v = 0.f, Z = 0.f;
  #pragma unroll
  for (int js = 0; js < 4; ++js){
    const float* p = accA + (size_t)js * N * TC + base;
    v += p[cc];
    Z += p[64];
  }
  float r = v / Z;
  xcat[(size_t)i * C1 + t] = f2b(lrelu(r, 0.01f));
}

// ---------------------------------------------------------------- k5: h2 = xcat@Wo, f1o/f2o (scaled), h2T rows 0..15
__global__ __launch_bounds__(256) void k5_h2(const uint16_t* __restrict__ xcat,
    const float* __restrict__ Wo, const float* __restrict__ ao,
    uint16_t* __restrict__ h2T, float* __restrict__ f1o, float* __restrict__ f2o)
{
  __shared__ uint16_t xs[16][256];
  int t = threadIdx.x;
  int i0 = blockIdx.x * 16;
  #pragma unroll
  for (int r = 0; r < 2; ++r){
    int idx = t + 256 * r;
    int ii = idx >> 5, o4 = idx & 31;
    *(uint4*)&xs[ii][o4 * 8] = *(const uint4*)(xcat + (size_t)(i0 + ii) * C1 + o4 * 8);
  }
  __syncthreads();
  int ii = t >> 4, c = t & 15;
  float acc = 0.f;
  for (int f = 0; f < 256; ++f)
    acc += b2f(xs[ii][f]) * Wo[f * 16 + c];
  int i = i0 + ii;
  h2T[(size_t)c * N + i] = f2b(acc);
  float u1 = acc * ao[c];
  float u2 = acc * ao[16 + c];
  #pragma unroll
  for (int off = 8; off; off >>= 1){
    u1 += __shfl_down(u1, off, 16);
    u2 += __shfl_down(u2, off, 16);
  }
  if (c == 0){ f1o[i] = u1 * LOG2E; f2o[i] = u2 * LOG2E; }
}

// ---------------------------------------------------------------- k6: phase-B masked-softmax GEMM (reg-Z, prefetch)
#define K6_BODY(JC, CUR, NXT)                                                    \
  {                                                                              \
    __syncthreads();                                                             \
    if (stg) *(uint4*)&Hl[p0][o40 * 8] = h##CUR;                                 \
    const int gjn = js * 1024 + (((JC) + 1) & 31) * 32;                          \
    if (stg) h##NXT = *(const uint4*)(h2T + (size_t)p0 * N + gjn + o40 * 8);     \
    _Pragma("unroll")                                                            \
    for (int r = 0; r < 8; ++r) av##NXT[r] = arow[(size_t)(8 * r) * N + gjn];    \
    f##NXT = f2o[gjn + tj];                                                      \
    _Pragma("unroll")                                                            \
    for (int rr = 0; rr < 4; ++rr){                                              \
      const int i0r = half + 16 * rr;                                            \
      const int i1r = i0r + 8;                                                   \
      float s0 = f1s[i0r] + f##CUR;                                              \
      float s1 = f1s[i1r] + f##CUR;                                              \
      float e0 = fexp2(fmaxf(s0, 0.2f * s0));                                    \
      float e1 = fexp2(fmaxf(s1, 0.2f * s1));                                    \
      if (av##CUR[2 * rr]     <= 0) e0 = 0.f;                                    \
      if (av##CUR[2 * rr + 1] <= 0) e1 = 0.f;                                    \
      dsum[2 * rr] += e0; dsum[2 * rr + 1] += e1;                                \
      uint32_t pk = pk_bf16(e0, e1);                                             \
      Pl[i0r][tj] = (uint16_t)pk; Pl[i1r][tj] = (uint16_t)(pk >> 16);            \
    }                                                                            \
    __syncthreads();                                                             \
    bf16x8 af = *(const bf16x8*)&Pl[wid * 16 + m][q * 8];                        \
    bf16x8 b0 = *(const bf16x8*)&Hl[m][q * 8];                                   \
    acc0 = __builtin_amdgcn_mfma_f32_16x16x32_bf16(af, b0, acc0, 0, 0, 0);       \
  }

__global__ __launch_bounds__(256) void k6_attB(const int* __restrict__ adj,
    const uint16_t* __restrict__ h2T, const float* __restrict__ f1o,
    const float* __restrict__ f2o, float* __restrict__ accB)
{
  __shared__ uint16_t Pl[64][40];
  __shared__ uint16_t Hl[16][40];
  __shared__ float f1s[64];

  const int t = threadIdx.x;
  const int ibl = blockIdx.x >> 3;
  const int js = blockIdx.x & 7;
  const int gi0 = ibl * 64;
  if (t < 64) f1s[t] = f1o[gi0 + t];

  const int tj = t & 31;
  const int half = t >> 5;          // 0..7
  const int lane = t & 63;
  const int wid = t >> 6;
  const int m = lane & 15;
  const int q = lane >> 4;

  const int p0 = t >> 2, o40 = t & 3;
  const bool stg = (t < 64);        // 16 rows x 4 chunks

  f32x4 acc0 = {0.f, 0.f, 0.f, 0.f};
  float dsum[8] = {};
  const int* arow = adj + (size_t)(gi0 + half) * N + tj;

  uint4 hA = {}, hB = {};
  int avA[8], avB[8];
  float fA, fB;

  {   // prologue: jc = 0
    const int gj0 = js * 1024;
    if (stg) hA = *(const uint4*)(h2T + (size_t)p0 * N + gj0 + o40 * 8);
    #pragma unroll
    for (int r = 0; r < 8; ++r) avA[r] = arow[(size_t)(8 * r) * N + gj0];
    fA = f2o[gj0 + tj];
  }

  for (int jc = 0; jc < 32; jc += 2){
    K6_BODY(jc,     A, B)
    K6_BODY(jc + 1, B, A)
  }

  #pragma unroll
  for (int reg = 0; reg < 4; ++reg){
    int gi = gi0 + wid * 16 + q * 4 + reg;
    accB[((size_t)js * N + gi) * C2 + m] = acc0[reg];
  }
  #pragma unroll
  for (int r = 0; r < 8; ++r){
    float v = dsum[r];
    v += __shfl_xor(v, 16);
    v += __shfl_xor(v, 8);
    v += __shfl_xor(v, 4);
    v += __shfl_xor(v, 2);
    v += __shfl_xor(v, 1);
    if (tj == 0)
      accB[((size_t)js * N + gi0 + half + 8 * r) * C2 + 16] = v;
  }
}

// ---------------------------------------------------------------- k7: reduce -> out (fp32)
__global__ void k7_redB(const float* __restrict__ accB, float* __restrict__ out){
  int idx = blockIdx.x * 256 + threadIdx.x;   // 131072
  int i = idx >> 4, c = idx & 15;
  float v = 0.f, Z = 0.f;
  #pragma unroll
  for (int js = 0; js < 8; ++js){
    const float* p = accB + ((size_t)js * N + i) * C2;
    v += p[c];
    Z += p[16];
  }
  out[idx] = v / Z;
}

// ================================================================ launch
extern "C" void kernel_launch(void* const* d_in, const int* in_sizes, int n_in,
                              void* d_out, int out_size, void* d_ws, size_t ws_size,
                              hipStream_t stream)
{
  const float* x   = (const float*)d_in[0];
  const int*   adj = (const int*)d_in[1];
  const float* Wh  = (const float*)d_in[2];
  const float* ah  = (const float*)d_in[3];
  const float* Wo  = (const float*)d_in[4];
  const float* ao  = (const float*)d_in[5];
  float* out = (float*)d_out;

  char* ws = (char*)d_ws;
  float*    WhT  = (float*)   (ws);                 // 512 KB  [4][64][512] fp32
  uint16_t* H    = (uint16_t*)(ws + 524288);        // 4 MB    [8192][256] bf16
  uint16_t* HT   = (uint16_t*)(ws + 4718592);       // 4 MB    [4][64][8192] bf16
  float*    f1   = (float*)   (ws + 8912896);       // 128 KB  (pre-scaled by log2e)
  float*    f2   = (float*)   (ws + 9043968);       // 128 KB
  float*    accA = (float*)   (ws + 9175040);       // 40 MB   [4][8192][320]
  uint16_t* xcat = (uint16_t*)(ws + 51118080);      // 4 MB    [8192][256] bf16
  uint16_t* h2T  = (uint16_t*)(ws + 55312384);      // 256 KB  [16][8192] bf16
  float*    f1o  = (float*)   (ws + 55574528);      // 32 KB
  float*    f2o  = (float*)   (ws + 55607296);      // 32 KB
  float*    accB = (float*)   (ws + 55640064);      // 8 MB    [8][8192][32]  (end 64028672)

  hipLaunchKernelGGL(k0_wht,   dim3(512),  dim3(256), 0, stream, Wh, WhT);
  hipLaunchKernelGGL(k1_h,     dim3(1024), dim3(256), 0, stream, x, WhT, ah, H, f1, f2);
  hipLaunchKernelGGL(k2a_htT,  dim3(512),  dim3(256), 0, stream, H, HT);
  hipLaunchKernelGGL(k3_attA,  dim3(512),  dim3(512), 0, stream, adj, HT, f1, f2, accA);
  hipLaunchKernelGGL(k4_redA,  dim3(8192), dim3(256), 0, stream, accA, xcat);
  hipLaunchKernelGGL(k5_h2,    dim3(512),  dim3(256), 0, stream, xcat, Wo, ao, h2T, f1o, f2o);
  hipLaunchKernelGGL(k6_attB,  dim3(1024), dim3(256), 0, stream, adj, h2T, f1o, f2o, accB);
  hipLaunchKernelGGL(k7_redB,  dim3(512),  dim3(256), 0, stream, accB, out);
}